// Round 1
// baseline (218.747 us; speedup 1.0000x reference)
//
#include <hip/hip_runtime.h>

// IoU distance: out[i][j] = inter/union + 1e-16
//   inter = min(lw_i, rw_j) * min(lh_i, rh_j)
//   union = lw_i*lh_i + rw_j*rh_j - inter
// lhs: (N, 2) fp32, rhs: (512, 2) fp32, out: (N, 512) fp32.
// Memory-bound on the 204.8 MB output write -> one float4 store per thread,
// consecutive threads = consecutive columns (coalesced). 512 = pow2 so all
// index math is shifts. rhs (4 KB) stays L1-resident.

#define NCOLS 512
#define COLS4 (NCOLS / 4)  // 128 float4 per output row

__global__ __launch_bounds__(256) void iou_kernel(
    const float2* __restrict__ lhs,
    const float2* __restrict__ rhs,
    float* __restrict__ out,
    int total4)
{
    int idx4 = blockIdx.x * blockDim.x + threadIdx.x;
    if (idx4 >= total4) return;

    int i  = idx4 >> 7;            // row (idx4 / 128)
    int j4 = (idx4 & (COLS4 - 1)) << 2;  // starting column

    float2 l = lhs[i];
    float la = l.x * l.y;          // lhs area

    // rhs[j4 .. j4+3] as two float4 loads (j4 multiple of 4 -> 32B aligned)
    const float4* rhs4 = (const float4*)rhs;
    float4 rA = rhs4[j4 >> 1];
    float4 rB = rhs4[(j4 >> 1) + 1];

    float rw[4] = {rA.x, rA.z, rB.x, rB.z};
    float rh[4] = {rA.y, rA.w, rB.y, rB.w};

    float res[4];
#pragma unroll
    for (int k = 0; k < 4; ++k) {
        float inter = fminf(l.x, rw[k]) * fminf(l.y, rh[k]);
        float uni   = fmaf(rw[k], rh[k], la) - inter;
        // v_rcp_f32 (~1 ulp) instead of IEEE div sequence; threshold is 2e-2
        res[k] = inter * __builtin_amdgcn_rcpf(uni) + 1e-16f;
    }

    float4 o = make_float4(res[0], res[1], res[2], res[3]);
    ((float4*)out)[idx4] = o;
}

extern "C" void kernel_launch(void* const* d_in, const int* in_sizes, int n_in,
                              void* d_out, int out_size, void* d_ws, size_t ws_size,
                              hipStream_t stream) {
    const float2* lhs = (const float2*)d_in[0];
    const float2* rhs = (const float2*)d_in[1];
    float* out = (float*)d_out;

    int n_lhs  = in_sizes[0] / 2;        // 100000
    int total4 = n_lhs * (NCOLS / 4);    // 12,800,000 float4 stores

    int block = 256;
    int grid  = (total4 + block - 1) / block;
    iou_kernel<<<grid, block, 0, stream>>>(lhs, rhs, out, total4);
}

// Round 3
// 210.725 us; speedup vs baseline: 1.0381x; 1.0381x over previous
//
#include <hip/hip_runtime.h>

// IoU distance: out[i][j] = inter/union + 1e-16, lhs (N,2), rhs (512,2), out (N,512) fp32.
//
// Structure: one wave per output row (grid-stride over rows). Each lane owns 8
// fixed columns: [4*lane, 4*lane+4) and [256+4*lane, 256+4*lane+4), so each of
// the wave's two float4 stores is a contiguous 1 KiB line-aligned burst.
// rhs (4 KB) is loaded ONCE per thread into registers (rw/rh/rw*rh precomputed),
// amortized over ~12 rows. Row index is wave-uniform (readfirstlane) so the lhs
// load and the output-row base address are scalar (s_load + saddr stores).
// ~6 VALU/element, v_rcp_f32 instead of IEEE div (absmax threshold 2e-2).

#define NCOLS 512

// Native vector type for __builtin_nontemporal_store (HIP's float4 class is rejected).
typedef float vfloat4 __attribute__((ext_vector_type(4)));

__global__ __launch_bounds__(256) void iou_kernel(
    const float2* __restrict__ lhs,
    const float*  __restrict__ rhs,
    float* __restrict__ out,
    int n_rows, int total_waves)
{
    const int tid  = blockIdx.x * blockDim.x + threadIdx.x;
    const int lane = threadIdx.x & 63;
    const int wave = __builtin_amdgcn_readfirstlane(tid >> 6);

    // Preload this lane's 8 columns of rhs into registers.
    // rhs4[c2] = {w[2c2], h[2c2], w[2c2+1], h[2c2+1]}
    const vfloat4* rhs4 = (const vfloat4*)rhs;
    vfloat4 a0 = rhs4[2 * lane];          // cols 4*lane, 4*lane+1
    vfloat4 a1 = rhs4[2 * lane + 1];      // cols 4*lane+2, 4*lane+3
    vfloat4 b0 = rhs4[128 + 2 * lane];    // cols 256+4*lane, ...
    vfloat4 b1 = rhs4[128 + 2 * lane + 1];

    float rw[8] = {a0.x, a0.z, a1.x, a1.z, b0.x, b0.z, b1.x, b1.z};
    float rh[8] = {a0.y, a0.w, a1.y, a1.w, b0.y, b0.w, b1.y, b1.w};
    float ra[8];
#pragma unroll
    for (int k = 0; k < 8; ++k) ra[k] = rw[k] * rh[k];

    for (int row = wave; row < n_rows; row += total_waves) {
        float2 l = lhs[row];             // wave-uniform -> scalar load
        float la = l.x * l.y;

        float o[8];
#pragma unroll
        for (int k = 0; k < 8; ++k) {
            float inter = fminf(l.x, rw[k]) * fminf(l.y, rh[k]);
            float uni   = (la + ra[k]) - inter;
            o[k] = fmaf(inter, __builtin_amdgcn_rcpf(uni), 1e-16f);
        }

        vfloat4* orow = (vfloat4*)(out + (size_t)row * NCOLS);
        vfloat4 v0 = {o[0], o[1], o[2], o[3]};
        vfloat4 v1 = {o[4], o[5], o[6], o[7]};
        __builtin_nontemporal_store(v0, orow + lane);        // cols 0..255
        __builtin_nontemporal_store(v1, orow + 64 + lane);   // cols 256..511
    }
}

extern "C" void kernel_launch(void* const* d_in, const int* in_sizes, int n_in,
                              void* d_out, int out_size, void* d_ws, size_t ws_size,
                              hipStream_t stream) {
    const float2* lhs = (const float2*)d_in[0];
    const float*  rhs = (const float*)d_in[1];
    float* out = (float*)d_out;

    int n_rows = in_sizes[0] / 2;    // 100000

    // 2048 blocks x 4 waves = 8192 waves; low VGPR use -> full occupancy,
    // each wave handles ~12 rows.
    int blocks = 2048;
    int total_waves = blocks * (256 / 64);
    iou_kernel<<<blocks, 256, 0, stream>>>(lhs, rhs, out, n_rows, total_waves);
}